// Round 1
// 150.193 us; speedup vs baseline: 1.0546x; 1.0546x over previous
//
#include <hip/hip_runtime.h>
#include <hip/hip_bf16.h>
#include <math.h>

#define PITCH_H 136   // halfs: 128 + 8 pad; rows stay 16B-aligned, bank stride non-pow2
#define LN2_F 0.69314718055994531f
#define WS_SHORTS 34816
#define WS_BYTES  69632                    // f16 weight fragments, all 4 layers
#define ACT_BYTES (8 * 32 * PITCH_H * 2)   // 8 waves x 32 rows x PITCH_H halfs
#define LDS_TOTAL (WS_BYTES + ACT_BYTES)   // 139264 B <= 160 KiB/CU

typedef _Float16 half8 __attribute__((ext_vector_type(8)));  // 8 f16 = 4 VGPRs (MFMA A/B frag)
typedef __attribute__((ext_vector_type(4))) float f32x4;     // MFMA C/D frag
typedef __attribute__((ext_vector_type(8))) short short8;

// ---------------- weight prep: fp32 W -> f16 in B-fragment order ----------------
// One thread = one (chunk, lane) unit: 8 strided W reads, one contiguous 16B store.
// Fragment layout for mfma_f32_16x16x32_f16:
//   B: lane l holds B[k = s*32 + (l>>4)*8 + j][n = ct*16 + (l&15)], j=0..7
// ws layout (shorts): chunk cp = s*NT + ct occupies 512 shorts at [cp*512 + lane*8 + j].
// Layer bases (shorts): L0=0 (64x128,CP16), L1=8192 (128x128,CP32), L2=24576 (128x64,CP16),
// L3=32768 (64x32,CP4). Total 34816 shorts = 69632 B.
__global__ void prep_weights(const float* __restrict__ W0, const float* __restrict__ W1,
                             const float* __restrict__ W2, const float* __restrict__ W3,
                             short* __restrict__ ws) {
    int e = blockIdx.x * 256 + threadIdx.x;     // unit id, 4352 total
    const float* W; int N, NT, base, ul;
    if (e < 1024)      { W = W0; N = 128; NT = 8; base = 0;     ul = e; }
    else if (e < 3072) { W = W1; N = 128; NT = 8; base = 8192;  ul = e - 1024; }
    else if (e < 4096) { W = W2; N = 64;  NT = 4; base = 24576; ul = e - 3072; }
    else if (e < 4352) { W = W3; N = 32;  NT = 2; base = 32768; ul = e - 4096; }
    else return;
    const int cp = ul >> 6, lane = ul & 63;
    const int s = cp / NT, ct = cp % NT;
    const int k0 = s * 32 + (lane >> 4) * 8;
    const int n = ct * 16 + (lane & 15);
    union { half8 h; short8 s; } v;
#pragma unroll
    for (int j = 0; j < 8; ++j) v.h[j] = (_Float16)W[(size_t)(k0 + j) * N + n];
    *(short8*)(ws + base + cp * 512 + lane * 8) = v.s;
}

// ---------------- per-wave layer compute: 2 m-tiles share every B fragment ----------------
// wf now points into LDS: B fragments come from ds_read_b128 (1KB contiguous per wave,
// conflict-free), ~120cyc latency hidden under the 16-MFMA slice body.
// bias is a lane-local register array indexed by compile-time ct.
template <int K, int N>
__device__ __forceinline__ void layer_frag2(const half8* wf,
                                            const float* bias,
                                            const half8 (&af)[2][4], int lane,
                                            f32x4 (&acc)[2][8]) {
    constexpr int NK = K / 32, NT = N / 16;
#pragma unroll
    for (int ct = 0; ct < NT; ++ct) {
        float b = bias[ct];
        acc[0][ct] = f32x4{b, b, b, b};
        acc[1][ct] = f32x4{b, b, b, b};
    }
#pragma unroll
    for (int s = 0; s < NK; ++s) {
#pragma unroll
        for (int ct = 0; ct < NT; ++ct) {
            half8 bh = wf[(s * NT + ct) * 64 + lane];
            // one B-load feeds two independent acc chains (ILP)
            acc[0][ct] = __builtin_amdgcn_mfma_f32_16x16x32_f16(af[0][s], bh, acc[0][ct], 0, 0, 0);
            acc[1][ct] = __builtin_amdgcn_mfma_f32_16x16x32_f16(af[1][s], bh, acc[1][ct], 0, 0, 0);
        }
    }
}

// A-fragments read straight from the f16 LDS tile: one ds_read_b128 per chunk, zero VALU.
template <int K>
__device__ __forceinline__ void load_a_lds(const _Float16* __restrict__ lw, int m, int q,
                                           half8 af[4]) {
    const _Float16* rp = lw + m * PITCH_H + q * 8;
#pragma unroll
    for (int s = 0; s < K / 32; ++s) af[s] = *(const half8*)(rp + s * 32);
}

template <int N>
__device__ __forceinline__ void store_d_lds(_Float16* __restrict__ lw, int m, int q,
                                            const f32x4* acc, bool relu) {
#pragma unroll
    for (int ct = 0; ct < N / 16; ++ct) {
#pragma unroll
        for (int r = 0; r < 4; ++r) {
            float v = acc[ct][r];
            if (relu) v = fmaxf(v, 0.0f);
            lw[(q * 4 + r) * PITCH_H + ct * 16 + m] = (_Float16)v;   // ds_write_b16
        }
    }
}

// Persistent: 256 blocks x 512 threads (8 waves), one block per CU (LDS-forced).
// Weights staged to LDS ONCE per block; each block loops over nchunks/256 chunks
// of 256 rows (32 rows per wave per iteration). No __syncthreads after staging.
__global__ __launch_bounds__(512, 2) void mlp_phi_mfma(
    const float* __restrict__ u,
    const float* __restrict__ b0, const float* __restrict__ b1,
    const float* __restrict__ b2, const float* __restrict__ b3,
    const short* __restrict__ ws,
    const float* __restrict__ var1, const float* __restrict__ var2,
    const float* __restrict__ var3, const float* __restrict__ var4,
    const float* __restrict__ var5, const float* __restrict__ var6,
    float* __restrict__ out, int nchunks) {
    extern __shared__ __align__(16) char smem[];
    short* wsl = (short*)smem;                        // 69632 B weight fragments
    _Float16* act = (_Float16*)(smem + WS_BYTES);     // 8 x 32 x PITCH_H f16 tiles

    const int t = threadIdx.x, lane = t & 63, wave = t >> 6;
    const int m = lane & 15, q = lane >> 4;

    // ---- stage all weight fragments global -> LDS (one time per block) ----
#pragma unroll 1
    for (int i = t; i < WS_SHORTS / 8; i += 512)
        ((short8*)wsl)[i] = ((const short8*)ws)[i];

    // ---- hoist biases + epilogue constants into registers (chunk-invariant) ----
    float bb0[8], bb1[8], bb2[4], bb3[2];
#pragma unroll
    for (int ct = 0; ct < 8; ++ct) bb0[ct] = b0[ct * 16 + m];
#pragma unroll
    for (int ct = 0; ct < 8; ++ct) bb1[ct] = b1[ct * 16 + m];
#pragma unroll
    for (int ct = 0; ct < 4; ++ct) bb2[ct] = b2[ct * 16 + m];
#pragma unroll
    for (int ct = 0; ct < 2; ++ct) bb3[ct] = b3[ct * 16 + m];

    float ev1[2], ev2[2], ev4[2], ev6[2], ev5h[2], ec3[2];
#pragma unroll
    for (int ot = 0; ot < 2; ++ot) {
        const int d = ot * 16 + m;
        ev1[ot] = var1[d]; ev2[ot] = var2[d]; ev4[ot] = var4[d]; ev6[ot] = var6[d];
        ev5h[ot] = 0.5f * var5[d];
        ec3[ot] = var3[d] - ev4[ot] - ev5h[ot];     // li coefficient, hoisted
    }

    __syncthreads();    // weights visible to all 8 waves; only barrier in the kernel

    const half8* wf0 = (const half8*)(wsl);
    const half8* wf1 = (const half8*)(wsl + 8192);
    const half8* wf2 = (const half8*)(wsl + 24576);
    const half8* wf3 = (const half8*)(wsl + 32768);
    _Float16* lw = act + wave * 32 * PITCH_H;

    half8 af[2][4];
    f32x4 acc[2][8];

#pragma unroll 1
    for (int c = blockIdx.x; c < nchunks; c += gridDim.x) {
        const size_t row0 = (size_t)c * 256 + wave * 32;

        // ---- Layer 0 (64 -> 128): A straight from global u, cvt fp32->f16 ----
#pragma unroll
        for (int mt = 0; mt < 2; ++mt) {
            const float* up = u + (row0 + mt * 16 + m) * 64;
#pragma unroll
            for (int s = 0; s < 2; ++s) {
                float4 v0 = *(const float4*)(up + s * 32 + q * 8);
                float4 v1 = *(const float4*)(up + s * 32 + q * 8 + 4);
                half8 a;
                a[0] = (_Float16)v0.x; a[1] = (_Float16)v0.y;
                a[2] = (_Float16)v0.z; a[3] = (_Float16)v0.w;
                a[4] = (_Float16)v1.x; a[5] = (_Float16)v1.y;
                a[6] = (_Float16)v1.z; a[7] = (_Float16)v1.w;
                af[mt][s] = a;
            }
        }
        layer_frag2<64, 128>(wf0, bb0, af, lane, acc);
#pragma unroll
        for (int mt = 0; mt < 2; ++mt) store_d_lds<128>(lw + mt * 16 * PITCH_H, m, q, acc[mt], true);

        // ---- Layer 1 (128 -> 128) ----
#pragma unroll
        for (int mt = 0; mt < 2; ++mt) load_a_lds<128>(lw + mt * 16 * PITCH_H, m, q, af[mt]);
        layer_frag2<128, 128>(wf1, bb1, af, lane, acc);
#pragma unroll
        for (int mt = 0; mt < 2; ++mt) store_d_lds<128>(lw + mt * 16 * PITCH_H, m, q, acc[mt], true);

        // ---- Layer 2 (128 -> 64) ----
#pragma unroll
        for (int mt = 0; mt < 2; ++mt) load_a_lds<128>(lw + mt * 16 * PITCH_H, m, q, af[mt]);
        layer_frag2<128, 64>(wf2, bb2, af, lane, acc);
#pragma unroll
        for (int mt = 0; mt < 2; ++mt) store_d_lds<64>(lw + mt * 16 * PITCH_H, m, q, acc[mt], true);

        // ---- Layer 3 (64 -> 32): net stays in registers ----
#pragma unroll
        for (int mt = 0; mt < 2; ++mt) load_a_lds<64>(lw + mt * 16 * PITCH_H, m, q, af[mt]);

        // Prefetch epilogue u values so their latency hides behind layer-3 MFMAs.
        float ue[2][8];
#pragma unroll
        for (int mt = 0; mt < 2; ++mt)
#pragma unroll
            for (int ot = 0; ot < 2; ++ot)
#pragma unroll
                for (int r = 0; r < 4; ++r)
                    ue[mt][ot * 4 + r] = u[(row0 + mt * 16 + q * 4 + r) * 64 + ot * 16 + m];

        layer_frag2<64, 32>(wf3, bb3, af, lane, acc);   // acc[mt][0..1] = net tiles

        // ---- Epilogue: lane holds net[row=mt*16+q*4+r][col=ot*16+m] ----
        // Domain note: u in [1e-4, 1-1e-4] => lt in [-9.22, -1e-4]; every quantity is
        // finite in fp32, so the reference's nan_to_num is a no-op here (checks dropped).
#pragma unroll
        for (int ot = 0; ot < 2; ++ot) {
            const int d = ot * 16 + m;
            const float v1 = ev1[ot], v2 = ev2[ot], v4 = ev4[ot], v6 = ev6[ot];
            const float v5h = ev5h[ot];
            const float c3 = ec3[ot];
#pragma unroll
            for (int mt = 0; mt < 2; ++mt) {
#pragma unroll
                for (int r = 0; r < 4; ++r) {
                    const size_t row = row0 + mt * 16 + q * 4 + r;
                    const float net = acc[mt][ot][r];
                    const float ud = ue[mt][ot * 4 + r];

                    const float omu = 1.0f - ud;
                    const float lt = __log2f(omu) * LN2_F;     // log(1-u) < 0
                    const float x = -lt;                        // in (1e-4, 9.3)

                    // E1 via Abramowitz-Stegun 5.1.53 (x<1) / 5.1.54 (x>=1)
                    const float e1s = -__log2f(x) * LN2_F
                        + (-0.57721566f + x * (0.99999193f + x * (-0.24991055f
                        + x * (0.05519968f + x * (-0.00976004f + x * 0.00107857f)))));
                    const float num = 0.2677737343f + x * (8.6347608925f + x * (18.0590169730f
                        + x * (8.5733287401f + x)));
                    const float den = 3.9584969228f + x * (21.0996530827f + x * (25.6329561486f
                        + x * (9.5733223454f + x)));
                    const float e1l = __expf(-x) * num * __builtin_amdgcn_rcpf(x * den);
                    const float li = -((x < 1.0f) ? e1s : e1l); // _li(1-u)

                    const float rl = __builtin_amdgcn_rcpf(lt); // 1/log_term
                    const float phi = fmaf(v4, omu, v2) * rl
                                    + (v5h * omu * (lt + 1.0f)) * rl * rl
                                    + c3 * li;

                    const float ud2 = ud * ud;
                    const float ud4 = ud2 * ud2;
                    const float p01 = ud4 * fmaf(-4.0f, ud, 5.0f);   // 5u^4 - 4u^5
                    const float corr1 = p01 * (v1 + phi);
                    const float d1 = ud - 1.0f;
                    const float corr2 = v6 * ud * d1 * d1;           // u^3 - 2u^2 + u

                    const float nt = fmaxf(net + corr1 + corr2, 0.0f);
                    const float base = fmaf(-0.5f, ud2, 0.5f);       // (1-u^2)/2
                    // base^(-nt) = exp2(-nt * log2(base)); v_exp_f32 is native exp2
                    out[row * 32 + d] = __builtin_amdgcn_exp2f(-nt * __log2f(base));
                }
            }
        }
    }
}

extern "C" void kernel_launch(void* const* d_in, const int* in_sizes, int n_in,
                              void* d_out, int out_size, void* d_ws, size_t ws_size,
                              hipStream_t stream) {
    const float* u    = (const float*)d_in[0];
    const float* W0   = (const float*)d_in[1];
    const float* b0   = (const float*)d_in[2];
    const float* W1   = (const float*)d_in[3];
    const float* b1   = (const float*)d_in[4];
    const float* W2   = (const float*)d_in[5];
    const float* b2   = (const float*)d_in[6];
    const float* W3   = (const float*)d_in[7];
    const float* b3   = (const float*)d_in[8];
    const float* var1 = (const float*)d_in[9];
    const float* var2 = (const float*)d_in[10];
    const float* var3 = (const float*)d_in[11];
    const float* var4 = (const float*)d_in[12];
    const float* var5 = (const float*)d_in[13];
    const float* var6 = (const float*)d_in[14];
    float* out = (float*)d_out;
    short* ws = (short*)d_ws;   // needs 69,632 B

    // Convert weights to f16 fragment layout (same work every launch).
    prep_weights<<<dim3(17), dim3(256), 0, stream>>>(W0, W1, W2, W3, ws);

    // Opt in to >64KB dynamic LDS (139,264 B; gfx950 has 160 KiB/CU). Idempotent.
    hipFuncSetAttribute(reinterpret_cast<const void*>(mlp_phi_mfma),
                        hipFuncAttributeMaxDynamicSharedMemorySize, LDS_TOTAL);

    const int B = in_sizes[0] / 64;        // 262144 rows
    const int nchunks = B / 256;           // 256 rows per chunk (32 per wave, 8 waves)
    const int nblocks = nchunks < 256 ? nchunks : 256;   // persistent: 1 block/CU
    mlp_phi_mfma<<<dim3(nblocks), dim3(512), LDS_TOTAL, stream>>>(
        u, b0, b1, b2, b3, ws,
        var1, var2, var3, var4, var5, var6, out, nchunks);
}